// Round 6
// baseline (243.894 us; speedup 1.0000x reference)
//
#include <hip/hip_runtime.h>
#include <math.h>

// MoE top-2 router. Round 9: homogeneous counted-vmcnt gld_lds pipeline.
// History: R4/R6 drained vmcnt(0) every chunk (latency exposed); R7's
// vmcnt(1) miscounted a MIXED queue (reg-loads + gld_lds); R5/R8 proved the
// compiler collapses register-prefetch rotations (VGPR 88/44). Fix: ALL
// staging via global_load_lds (pinned, homogeneous vmcnt), 32-token blocks,
// x 4-buffered (3 chunks ahead), W hi/lo 2-buffered (1 ahead, L2-hot),
// exact ledger -> s_waitcnt vmcnt(1) steady state, never 0 in the loop.
// LDS 64 KB exactly -> 2 blocks/CU. Compute/epilogue = R6-verified.
//
// x: [16384, 2048] fp32, W: [64, 2048] fp32.
// outputs (concat, fp32): mask [T,64], idx-as-float [T,2],
//                         router_probs [T,64], probs [T,64]

#define D_DIM 2048
#define E_DIM 64
#define NCH   (D_DIM >> 6)   // 32 chunks of 64 k

typedef __bf16 bf16x8 __attribute__((ext_vector_type(8)));
typedef unsigned short us8 __attribute__((ext_vector_type(8)));
typedef float f32x4 __attribute__((ext_vector_type(4)));

static __device__ __forceinline__ unsigned short f2bf(float f) {
    unsigned int u = __float_as_uint(f);
    u += 0x7fffu + ((u >> 16) & 1u);   // RNE
    return (unsigned short)(u >> 16);
}
static __device__ __forceinline__ float bf2f(unsigned short h) {
    return __uint_as_float(((unsigned int)h) << 16);
}
static __device__ __forceinline__ void split4(const float4 v, ushort4* h, ushort4* l) {
    h->x = f2bf(v.x); l->x = f2bf(v.x - bf2f(h->x));
    h->y = f2bf(v.y); l->y = f2bf(v.y - bf2f(h->y));
    h->z = f2bf(v.z); l->z = f2bf(v.z - bf2f(h->z));
    h->w = f2bf(v.w); l->w = f2bf(v.w - bf2f(h->w));
}

static __device__ __forceinline__ void gld_lds16(const void* g, void* l) {
    __builtin_amdgcn_global_load_lds(
        (const __attribute__((address_space(1))) unsigned int*)g,
        (__attribute__((address_space(3))) unsigned int*)l,
        16, 0, 0);
}

// ---- pre-convert W (64x2048 fp32) -> bf16 hi/lo, linear layout ----
__global__ __launch_bounds__(256, 1) void convert_w(
    const float4* __restrict__ W4, unsigned short* __restrict__ WH,
    unsigned short* __restrict__ WL)
{
    int i = blockIdx.x * 256 + threadIdx.x;   // float4 index
    float4 v = W4[i];
    ushort4 h, l;
    split4(v, &h, &l);
    *(ushort4*)&WH[i * 4] = h;
    *(ushort4*)&WL[i * 4] = l;
}

// ---- fused GEMM + softmax + top-2 + outputs ----
// block = 32 tokens x 64 experts x K=2048; 256 threads (4 waves);
// wave wv computes expert tile [wv*16, wv*16+16) for both 16-token halves.
__global__ __launch_bounds__(256, 2) void router_fused(
    const float* __restrict__ x,
    const unsigned short* __restrict__ WHg, const unsigned short* __restrict__ WLg,
    float* __restrict__ mask_out, float* __restrict__ idx_out,
    float* __restrict__ rp_out, float* __restrict__ probs_out)
{
    // 16B-slot-swizzled tiles (R6-verified swizzle). 64 KB total.
    __shared__ __align__(16) float          XF [4][32 * 64];  // 4x 8 KB fp32 x
    __shared__ __align__(16) unsigned short WHs[2][64 * 64];  // 2x 8 KB
    __shared__ __align__(16) unsigned short WLs[2][64 * 64];  // 2x 8 KB

    const int tid  = threadIdx.x;
    const int lane = tid & 63;
    const int wv   = tid >> 6;
    const int quad = lane >> 4;
    const int l16  = lane & 15;

    const int t0 = blockIdx.x << 5;

    f32x4 acc[2];
    {
        f32x4 z = {0.f, 0.f, 0.f, 0.f};
        acc[0] = z; acc[1] = z;
    }

    // x staging lanes: rows xr0 (+16), swizzled float4 col xc (same for both
    // groups since (xr0+16)&15 == xr0&15).
    const int xr0 = wv * 4 + (lane >> 4);
    const int xc  = (lane & 15) ^ (xr0 & 15);
    // W staging lanes: experts we0 (+32), swizzled k-octet wo.
    const int we0 = wv * 8 + (lane >> 3);
    const int wo  = (lane & 7) ^ (we0 & 7);

    // compute-side constants
    const int e  = wv * 16 + l16;      // this lane's expert (B-fragment row)
    const int e8 = e * 8;
    const int ek = e & 7;

#define STAGE_X(cc, xi) do {                                                   \
        const int _kc = (cc) << 6;                                             \
        gld_lds16(x + (size_t)(t0 + xr0) * D_DIM + _kc + xc * 4,               \
                  &XF[xi][(wv * 64) * 4]);                                     \
        gld_lds16(x + (size_t)(t0 + 16 + xr0) * D_DIM + _kc + xc * 4,          \
                  &XF[xi][(256 + wv * 64) * 4]);                               \
    } while (0)

#define STAGE_W(cc, wi) do {                                                   \
        const int _kc = (cc) << 6;                                             \
        gld_lds16(WHg + (size_t)we0 * D_DIM + _kc + wo * 8,                    \
                  &WHs[wi][(wv * 64) * 8]);                                    \
        gld_lds16(WHg + (size_t)(32 + we0) * D_DIM + _kc + wo * 8,             \
                  &WHs[wi][(256 + wv * 64) * 8]);                              \
        gld_lds16(WLg + (size_t)we0 * D_DIM + _kc + wo * 8,                    \
                  &WLs[wi][(wv * 64) * 8]);                                    \
        gld_lds16(WLg + (size_t)(32 + we0) * D_DIM + _kc + wo * 8,             \
                  &WLs[wi][(256 + wv * 64) * 8]);                              \
    } while (0)

#define COMPUTE(wb_, xb_) do {                                                 \
        _Pragma("unroll")                                                      \
        for (int ks = 0; ks < 2; ++ks) {                                       \
            const int o  = ks * 4 + quad;                                      \
            const int sW = e8 + (o ^ ek);                                      \
            bf16x8 bh = *(const bf16x8*)&WHs[wb_][sW * 8];                     \
            bf16x8 bl = *(const bf16x8*)&WLs[wb_][sW * 8];                     \
            _Pragma("unroll")                                                  \
            for (int th = 0; th < 2; ++th) {                                   \
                const int tr = th * 16 + l16;                                  \
                const int c0 = ks * 8 + quad * 2;                              \
                float4 va = *(const float4*)                                   \
                    &XF[xb_][(tr * 16 + ( c0      ^ l16)) * 4];                \
                float4 vb = *(const float4*)                                   \
                    &XF[xb_][(tr * 16 + ((c0 + 1) ^ l16)) * 4];                \
                ushort4 h0, l0, h1, l1;                                        \
                split4(va, &h0, &l0);                                          \
                split4(vb, &h1, &l1);                                          \
                union { us8 u; bf16x8 b; } ua, ul;                             \
                ua.u = (us8){h0.x, h0.y, h0.z, h0.w, h1.x, h1.y, h1.z, h1.w};  \
                ul.u = (us8){l0.x, l0.y, l0.z, l0.w, l1.x, l1.y, l1.z, l1.w};  \
                acc[th] = __builtin_amdgcn_mfma_f32_16x16x32_bf16(             \
                    ua.b, bh, acc[th], 0, 0, 0);                               \
                acc[th] = __builtin_amdgcn_mfma_f32_16x16x32_bf16(             \
                    ul.b, bh, acc[th], 0, 0, 0);                               \
                acc[th] = __builtin_amdgcn_mfma_f32_16x16x32_bf16(             \
                    ua.b, bl, acc[th], 0, 0, 0);                               \
            }                                                                  \
        }                                                                      \
    } while (0)

#define BARX() do {                                                            \
        __builtin_amdgcn_sched_barrier(0);                                     \
        __builtin_amdgcn_s_barrier();                                          \
        __builtin_amdgcn_sched_barrier(0);                                     \
    } while (0)

    // ---- prologue (matches steady-state issue order: x(ch) ... W(ch) ...) ----
    STAGE_X(0, 0);
    STAGE_X(1, 1);
    STAGE_W(0, 0);
    STAGE_X(2, 2);

    // ---- main loop. Ledger at the wait (oldest->newest, per thread):
    // x(ch+1)[1], W(ch)[4], x(ch+2)[1] = 6 outstanding; prefix through W(ch)
    // leaves 1 -> vmcnt(1). Loads stay in flight ACROSS the barrier.
    for (int ch = 0; ch <= 28; ++ch) {
        asm volatile("s_waitcnt vmcnt(1)" ::: "memory");
        BARX();
        STAGE_W(ch + 1, (ch + 1) & 1);
        STAGE_X(ch + 3, (ch + 3) & 3);
        COMPUTE(ch & 1, ch & 3);
    }
    // ch = 29: outstanding x(30), W(29), x(31) -> vmcnt(1); no x to stage
    asm volatile("s_waitcnt vmcnt(1)" ::: "memory");
    BARX();
    STAGE_W(30, 0);
    COMPUTE(1, 1);
    // ch = 30: outstanding x(31), W(30) -> drain (tail)
    asm volatile("s_waitcnt vmcnt(0)" ::: "memory");
    BARX();
    STAGE_W(31, 1);
    COMPUTE(0, 2);
    // ch = 31: outstanding W(31) -> drain
    asm volatile("s_waitcnt vmcnt(0)" ::: "memory");
    BARX();
    COMPUTE(1, 3);

    // ---- epilogue: exchange 16-expert slices via LDS, then 64-lane reduce ----
    // acc[th][r] = logit(token = th*16 + quad*4 + r, expert = wv*16 + l16).
    // XF[0] last read at compute(28); barriers 29..31 separate all waves'
    // reads from these writes.
    float* L = (float*)&XF[0][0];              // 8 KB = [32 tokens][64 experts]
    #pragma unroll
    for (int th = 0; th < 2; ++th)
        #pragma unroll
        for (int r = 0; r < 4; ++r)
            L[(th * 16 + quad * 4 + r) * 64 + wv * 16 + l16] = acc[th][r];
    __syncthreads();

    for (int i = 0; i < 8; ++i) {
        const int tl = wv * 8 + i;             // token within block
        const int t  = t0 + tl;
        const float v = L[tl * 64 + lane];

        // argmax, lower-index tie-break (matches jax.lax.top_k)
        float bv = v; int bi = lane;
        #pragma unroll
        for (int off = 1; off < 64; off <<= 1) {
            float ov = __shfl_xor(bv, off, 64);
            int   oi = __shfl_xor(bi, off, 64);
            bool take = (ov > bv) || (ov == bv && oi < bi);
            bv = take ? ov : bv;
            bi = take ? oi : bi;
        }
        const float m = bv; const int i1 = bi;

        const float p = __expf(v - m);
        float s = p;
        #pragma unroll
        for (int off = 1; off < 64; off <<= 1) s += __shfl_xor(s, off, 64);
        const float prob = p / s;

        // second argmax excluding i1
        const float v2 = (lane == i1) ? -INFINITY : v;
        float cv = v2; int ci = lane;
        #pragma unroll
        for (int off = 1; off < 64; off <<= 1) {
            float ov = __shfl_xor(cv, off, 64);
            int   oi = __shfl_xor(ci, off, 64);
            bool take = (ov > cv) || (ov == cv && oi < ci);
            cv = take ? ov : cv;
            ci = take ? oi : ci;
        }
        const int i2 = ci;

        const float pd = __shfl(prob, i1, 64) + __shfl(prob, i2, 64);
        const bool top = (lane == i1) || (lane == i2);

        const size_t base = (size_t)t * 64 + lane;
        mask_out[base]  = top ? 1.f : 0.f;
        rp_out[base]    = top ? prob / pd : 0.f;
        probs_out[base] = prob;
        if (lane == 0) {
            idx_out[(size_t)t * 2]     = (float)i1;
            idx_out[(size_t)t * 2 + 1] = (float)i2;
        }
    }
#undef STAGE_X
#undef STAGE_W
#undef COMPUTE
#undef BARX
}

extern "C" void kernel_launch(void* const* d_in, const int* in_sizes, int n_in,
                              void* d_out, int out_size, void* d_ws, size_t ws_size,
                              hipStream_t stream) {
    const float* x = (const float*)d_in[0];
    const float* W = (const float*)d_in[1];
    float* out = (float*)d_out;

    const int T  = in_sizes[0] / D_DIM;     // 16384 tokens
    const int WN = in_sizes[1];             // 131072 elements

    unsigned short* WH = (unsigned short*)d_ws;
    unsigned short* WL = WH + WN;           // total ws use: 512 KB

    float* mask_out  = out;
    float* idx_out   = out + (size_t)T * E_DIM;
    float* rp_out    = idx_out + (size_t)T * 2;
    float* probs_out = rp_out + (size_t)T * E_DIM;

    convert_w<<<dim3(WN / 1024), dim3(256), 0, stream>>>((const float4*)W, WH, WL);
    router_fused<<<dim3(T / 32), dim3(256), 0, stream>>>(
        x, WH, WL, mask_out, idx_out, rp_out, probs_out);
}